// Round 2
// baseline (2547.748 us; speedup 1.0000x reference)
//
#include <hip/hip_runtime.h>
#include <hip/hip_bf16.h>

#define N_NODES 200000
#define N_EDGES 1200000
#define IN_DIM  128
#define HID     64
#define NGRAPH  1024
#define NCLS    6
#define BN_EPS  1e-5f

// ---------------------------------------------------------------------------
// Embed: h = relu(bn(x @ W + b)), and zero agg for layer 0's scatter.
// One wave handles 4 nodes; x row held in registers (lane k holds x[k], x[k+64]),
// broadcast via __shfl; W staged in LDS.
// ---------------------------------------------------------------------------
__global__ __launch_bounds__(256) void embed_kernel(
    const float* __restrict__ x,      // [N,128]
    const float* __restrict__ w,      // [128,64]
    const float* __restrict__ bias,   // [64]
    const float* __restrict__ bn_g, const float* __restrict__ bn_b,
    const float* __restrict__ bn_m, const float* __restrict__ bn_v,
    float* __restrict__ h,            // [N,64]
    float* __restrict__ agg)          // [N,64] zero-filled here
{
    __shared__ float Wl[IN_DIM * HID];         // 32 KiB
    const int t = threadIdx.x, lane = t & 63, grp = t >> 6;
    for (int i = t; i < IN_DIM * HID; i += 256) Wl[i] = w[i];
    const float scale = bn_g[lane] * rsqrtf(bn_v[lane] + BN_EPS);
    const float shift = bias[lane] * scale + bn_b[lane] - bn_m[lane] * scale;
    __syncthreads();

    const int base = blockIdx.x * 256 + grp * 4;   // this wave's first node
    for (int i = 0; i < 256; i += 16) {
        const int n0 = base + i;
        if (n0 >= N_NODES) break;                  // N % 4 == 0 -> 4 nodes all valid
        float xlo[4], xhi[4];
        #pragma unroll
        for (int j = 0; j < 4; j++) {
            xlo[j] = x[(size_t)(n0 + j) * IN_DIM + lane];
            xhi[j] = x[(size_t)(n0 + j) * IN_DIM + 64 + lane];
        }
        float a[4] = {0.f, 0.f, 0.f, 0.f};
        #pragma unroll
        for (int k = 0; k < 64; k++) {
            const float wv = Wl[k * HID + lane];
            a[0] += __shfl(xlo[0], k, 64) * wv;
            a[1] += __shfl(xlo[1], k, 64) * wv;
            a[2] += __shfl(xlo[2], k, 64) * wv;
            a[3] += __shfl(xlo[3], k, 64) * wv;
        }
        #pragma unroll
        for (int k = 0; k < 64; k++) {
            const float wv = Wl[(k + 64) * HID + lane];
            a[0] += __shfl(xhi[0], k, 64) * wv;
            a[1] += __shfl(xhi[1], k, 64) * wv;
            a[2] += __shfl(xhi[2], k, 64) * wv;
            a[3] += __shfl(xhi[3], k, 64) * wv;
        }
        #pragma unroll
        for (int j = 0; j < 4; j++) {
            const size_t o = (size_t)(n0 + j) * HID + lane;
            h[o] = fmaxf(a[j] * scale + shift, 0.f);
            agg[o] = 0.f;
        }
    }
}

// ---------------------------------------------------------------------------
// Scatter: agg[dst] += h[src] — one wave per edge, lane = channel.
// ---------------------------------------------------------------------------
__global__ __launch_bounds__(256) void scatter_kernel(
    const int* __restrict__ src, const int* __restrict__ dst,
    const float* __restrict__ h, float* __restrict__ agg)
{
    const int wid = (blockIdx.x * 256 + threadIdx.x) >> 6;  // edge id
    const int lane = threadIdx.x & 63;
    if (wid < N_EDGES) {
        const int s = src[wid], d = dst[wid];
        atomicAdd(&agg[(size_t)d * HID + lane], h[(size_t)s * HID + lane]);
    }
}

// ---------------------------------------------------------------------------
// Fused GIN MLP: z = h+agg; z = relu(bn1(z@W1+b1)); h = relu(bn2(z@W2+b2)).
// One wave handles 4 nodes; folded-BN per-channel consts; W1/W2 in LDS.
// Optionally re-zeroes agg for the next layer's scatter.
// ---------------------------------------------------------------------------
__global__ __launch_bounds__(256) void mlp_kernel(
    const float* __restrict__ w1, const float* __restrict__ b1,
    const float* __restrict__ g1, const float* __restrict__ bb1,
    const float* __restrict__ m1, const float* __restrict__ v1,
    const float* __restrict__ w2, const float* __restrict__ b2,
    const float* __restrict__ g2, const float* __restrict__ bb2,
    const float* __restrict__ m2, const float* __restrict__ v2,
    float* __restrict__ h, float* __restrict__ agg, int zero_agg)
{
    __shared__ float W1[HID * HID];   // 16 KiB
    __shared__ float W2[HID * HID];   // 16 KiB
    const int t = threadIdx.x, lane = t & 63, grp = t >> 6;
    for (int i = t; i < HID * HID; i += 256) {
        W1[i] = w1[i];
        W2[i] = w2[i];
    }
    const float s1 = g1[lane] * rsqrtf(v1[lane] + BN_EPS);
    const float c1 = b1[lane] * s1 + bb1[lane] - m1[lane] * s1;
    const float s2 = g2[lane] * rsqrtf(v2[lane] + BN_EPS);
    const float c2 = b2[lane] * s2 + bb2[lane] - m2[lane] * s2;
    __syncthreads();

    const int base = blockIdx.x * 256 + grp * 4;
    for (int i = 0; i < 256; i += 16) {
        const int n0 = base + i;
        if (n0 >= N_NODES) break;
        float z[4];
        #pragma unroll
        for (int j = 0; j < 4; j++) {
            const size_t o = (size_t)(n0 + j) * HID + lane;
            z[j] = h[o] + agg[o];
            if (zero_agg) agg[o] = 0.f;
        }
        float a[4] = {0.f, 0.f, 0.f, 0.f};
        #pragma unroll
        for (int k = 0; k < HID; k++) {
            const float wv = W1[k * HID + lane];
            a[0] += __shfl(z[0], k, 64) * wv;
            a[1] += __shfl(z[1], k, 64) * wv;
            a[2] += __shfl(z[2], k, 64) * wv;
            a[3] += __shfl(z[3], k, 64) * wv;
        }
        float t1[4];
        #pragma unroll
        for (int j = 0; j < 4; j++) t1[j] = fmaxf(a[j] * s1 + c1, 0.f);
        float o2[4] = {0.f, 0.f, 0.f, 0.f};
        #pragma unroll
        for (int k = 0; k < HID; k++) {
            const float wv = W2[k * HID + lane];
            o2[0] += __shfl(t1[0], k, 64) * wv;
            o2[1] += __shfl(t1[1], k, 64) * wv;
            o2[2] += __shfl(t1[2], k, 64) * wv;
            o2[3] += __shfl(t1[3], k, 64) * wv;
        }
        #pragma unroll
        for (int j = 0; j < 4; j++)
            h[(size_t)(n0 + j) * HID + lane] = fmaxf(o2[j] * s2 + c2, 0.f);
    }
}

// ---------------------------------------------------------------------------
// Pool: batch is sorted, so accumulate runs in registers, flush one atomic
// per (wave, graph-transition). Lane = channel.
// ---------------------------------------------------------------------------
__global__ __launch_bounds__(256) void pool_kernel(
    const float* __restrict__ h, const int* __restrict__ batch,
    float* __restrict__ pooled /*[G,64]*/, float* __restrict__ cnt /*[G]*/)
{
    const int CHUNK = 256;
    const int wid = (blockIdx.x * 256 + threadIdx.x) >> 6;
    const int lane = threadIdx.x & 63;
    const int start = wid * CHUNK;
    if (start >= N_NODES) return;
    const int end = (start + CHUNK < N_NODES) ? (start + CHUNK) : N_NODES;
    int cur = batch[start];
    float acc = 0.f, c = 0.f;
    for (int n = start; n < end; n++) {
        const int g = batch[n];             // wave-uniform (sorted batch)
        if (g != cur) {
            atomicAdd(&pooled[(size_t)cur * HID + lane], acc);
            if (lane == 0) atomicAdd(&cnt[cur], c);
            cur = g; acc = 0.f; c = 0.f;
        }
        acc += h[(size_t)n * HID + lane];
        c += 1.f;
    }
    atomicAdd(&pooled[(size_t)cur * HID + lane], acc);
    if (lane == 0) atomicAdd(&cnt[cur], c);
}

// ---------------------------------------------------------------------------
// Classifier: per graph, p = pooled/cnt; out = relu(p@W1+b1)@W2+b2.
// ---------------------------------------------------------------------------
__global__ __launch_bounds__(64) void cls_kernel(
    const float* __restrict__ pooled, const float* __restrict__ cnt,
    const float* __restrict__ w1, const float* __restrict__ b1, // [64,32],[32]
    const float* __restrict__ w2, const float* __restrict__ b2, // [32,6],[6]
    float* __restrict__ out)      // [G,6]
{
    const int g = blockIdx.x;
    const int lane = threadIdx.x;
    const float c = cnt[g];
    const float p = pooled[(size_t)g * HID + lane] / fmaxf(c, 1.f);
    float acc = (lane < 32) ? b1[lane] : 0.f;
    #pragma unroll
    for (int k = 0; k < 64; k++) {
        const float pk = __shfl(p, k, 64);
        if (lane < 32) acc += pk * w1[k * 32 + lane];
    }
    const float hmid = fmaxf(acc, 0.f);
    float acc2 = (lane < NCLS) ? b2[lane] : 0.f;
    #pragma unroll
    for (int k = 0; k < 32; k++) {
        const float hk = __shfl(hmid, k, 64);
        if (lane < NCLS) acc2 += hk * w2[k * NCLS + lane];
    }
    if (lane < NCLS) out[(size_t)g * NCLS + lane] = acc2;
}

// ---------------------------------------------------------------------------
extern "C" void kernel_launch(void* const* d_in, const int* in_sizes, int n_in,
                              void* d_out, int out_size, void* d_ws, size_t ws_size,
                              hipStream_t stream) {
    const float* x     = (const float*)d_in[0];
    const int*   ei    = (const int*)d_in[1];            // [2,E]
    const int*   batch = (const int*)d_in[2];
    const float* emb_w = (const float*)d_in[3];
    const float* emb_b = (const float*)d_in[4];
    const float* ibn_g = (const float*)d_in[5];
    const float* ibn_b = (const float*)d_in[6];
    const float* ibn_m = (const float*)d_in[7];
    const float* ibn_v = (const float*)d_in[8];
    const float* fc1_w = (const float*)d_in[9];
    const float* fc1_b = (const float*)d_in[10];
    const float* mbn_g = (const float*)d_in[11];
    const float* mbn_b = (const float*)d_in[12];
    const float* mbn_m = (const float*)d_in[13];
    const float* mbn_v = (const float*)d_in[14];
    const float* fc2_w = (const float*)d_in[15];
    const float* fc2_b = (const float*)d_in[16];
    const float* obn_g = (const float*)d_in[17];
    const float* obn_b = (const float*)d_in[18];
    const float* obn_m = (const float*)d_in[19];
    const float* obn_v = (const float*)d_in[20];
    const float* cls1w = (const float*)d_in[21];
    const float* cls1b = (const float*)d_in[22];
    const float* cls2w = (const float*)d_in[23];
    const float* cls2b = (const float*)d_in[24];

    float* h      = (float*)d_ws;
    float* agg    = h + (size_t)N_NODES * HID;
    float* pooled = agg + (size_t)N_NODES * HID;
    float* cnt    = pooled + (size_t)NGRAPH * HID;

    hipMemsetAsync(pooled, 0, (size_t)(NGRAPH * HID + NGRAPH) * sizeof(float), stream);

    const int node_blocks = (N_NODES + 255) / 256;   // 782
    embed_kernel<<<node_blocks, 256, 0, stream>>>(x, emb_w, emb_b,
                                                  ibn_g, ibn_b, ibn_m, ibn_v, h, agg);

    for (int i = 0; i < 3; i++) {
        scatter_kernel<<<N_EDGES / 4, 256, 0, stream>>>(ei, ei + N_EDGES, h, agg);
        mlp_kernel<<<node_blocks, 256, 0, stream>>>(
            fc1_w + i * HID * HID, fc1_b + i * HID,
            mbn_g + i * HID, mbn_b + i * HID, mbn_m + i * HID, mbn_v + i * HID,
            fc2_w + i * HID * HID, fc2_b + i * HID,
            obn_g + i * HID, obn_b + i * HID, obn_m + i * HID, obn_v + i * HID,
            h, agg, (i < 2) ? 1 : 0);
    }

    const int pool_waves = (N_NODES + 255) / 256;    // 782 waves
    pool_kernel<<<(pool_waves + 3) / 4, 256, 0, stream>>>(h, batch, pooled, cnt);

    cls_kernel<<<NGRAPH, 64, 0, stream>>>(pooled, cnt, cls1w, cls1b, cls2w, cls2b,
                                          (float*)d_out);
}

// Round 3
// 1372.353 us; speedup vs baseline: 1.8565x; 1.8565x over previous
//
#include <hip/hip_runtime.h>
#include <hip/hip_bf16.h>

#define N_NODES 200000
#define N_EDGES 1200000
#define IN_DIM  128
#define HID     64
#define NGRAPH  1024
#define NCLS    6
#define BN_EPS  1e-5f

#define TILE_N   64          // nodes per block
#define ZSTRIDE  132         // padded row stride (floats); 528 B, 16B-aligned, bank-safe

// ---------------------------------------------------------------------------
// Register-blocked LDS GEMM kernels.
// Thread map: cgrp = t&15 (4 channels c0=cgrp*4), ngrp = t>>4 (4 nodes
// n = ngrp + 16j). Inner loop: per 4-k step, 4 z b128 + 4 w b128 reads feed
// 64 FMAs -> VALU-bound (DS ~88 cyc vs VALU 128 cyc per step).
// ---------------------------------------------------------------------------

// Embed: h = relu(bn(x @ W + b)); also zero agg. K=128 staged in two halves.
__global__ __launch_bounds__(256) void embed_kernel(
    const float* __restrict__ x,      // [N,128]
    const float* __restrict__ w,      // [128,64]
    const float* __restrict__ bias,   // [64]
    const float* __restrict__ bn_g, const float* __restrict__ bn_b,
    const float* __restrict__ bn_m, const float* __restrict__ bn_v,
    float* __restrict__ h,            // [N,64]
    float* __restrict__ agg)          // [N,64] zero-filled here
{
    __shared__ float Z[TILE_N * ZSTRIDE];   // 33792 B (x tile, 64x128 padded)
    __shared__ float Wl[64 * HID];          // 16384 B (one K-half of W)
    const int t = threadIdx.x;
    const int cgrp = t & 15, ngrp = t >> 4;
    const int c0 = cgrp * 4;
    const int base = blockIdx.x * TILE_N;

    // stage x tile: 64 rows x 32 float4, coalesced
    #pragma unroll
    for (int i = 0; i < 8; i++) {
        const int idx = t + i * 256;            // 0..2047
        const int n = idx >> 5, k4 = idx & 31;
        const float4 v = *(const float4*)(x + (size_t)(base + n) * IN_DIM + k4 * 4);
        *(float4*)(&Z[n * ZSTRIDE + k4 * 4]) = v;
    }

    // folded BN consts for this thread's 4 channels
    float scale[4], shift[4];
    #pragma unroll
    for (int cc = 0; cc < 4; cc++) {
        const int c = c0 + cc;
        const float s = bn_g[c] * rsqrtf(bn_v[c] + BN_EPS);
        scale[cc] = s;
        shift[cc] = bias[c] * s + bn_b[c] - bn_m[c] * s;
    }

    float acc[4][4] = {};
    for (int kh = 0; kh < 2; kh++) {
        // stage W K-half: 64x64 floats = 1024 float4
        __syncthreads();                        // protect Wl reuse
        #pragma unroll
        for (int i = 0; i < 4; i++) {
            const int idx = t + i * 256;        // 0..1023
            const int k = idx >> 4, k4 = idx & 15;
            *(float4*)(&Wl[k * HID + k4 * 4]) =
                *(const float4*)(w + (size_t)(kh * 64 + k) * HID + k4 * 4);
        }
        __syncthreads();

        #pragma unroll
        for (int k4 = 0; k4 < 16; k4++) {
            float4 zv[4], wv[4];
            #pragma unroll
            for (int j = 0; j < 4; j++)
                zv[j] = *(const float4*)(&Z[(ngrp + 16 * j) * ZSTRIDE + (kh * 16 + k4) * 4]);
            #pragma unroll
            for (int i = 0; i < 4; i++)
                wv[i] = *(const float4*)(&Wl[(k4 * 4 + i) * HID + c0]);
            #pragma unroll
            for (int j = 0; j < 4; j++) {
                const float z0 = zv[j].x, z1 = zv[j].y, z2 = zv[j].z, z3 = zv[j].w;
                acc[j][0] += z0 * wv[0].x + z1 * wv[1].x + z2 * wv[2].x + z3 * wv[3].x;
                acc[j][1] += z0 * wv[0].y + z1 * wv[1].y + z2 * wv[2].y + z3 * wv[3].y;
                acc[j][2] += z0 * wv[0].z + z1 * wv[1].z + z2 * wv[2].z + z3 * wv[3].z;
                acc[j][3] += z0 * wv[0].w + z1 * wv[1].w + z2 * wv[2].w + z3 * wv[3].w;
            }
        }
    }

    const float4 zero4 = make_float4(0.f, 0.f, 0.f, 0.f);
    #pragma unroll
    for (int j = 0; j < 4; j++) {
        const int n = base + ngrp + 16 * j;
        float4 o;
        o.x = fmaxf(acc[j][0] * scale[0] + shift[0], 0.f);
        o.y = fmaxf(acc[j][1] * scale[1] + shift[1], 0.f);
        o.z = fmaxf(acc[j][2] * scale[2] + shift[2], 0.f);
        o.w = fmaxf(acc[j][3] * scale[3] + shift[3], 0.f);
        *(float4*)(h + (size_t)n * HID + c0) = o;        // coalesced: 4x256B rows/instr
        *(float4*)(agg + (size_t)n * HID + c0) = zero4;
    }
}

// ---------------------------------------------------------------------------
// Scatter: agg[dst] += h[src] — one wave per edge, lane = channel.
// ---------------------------------------------------------------------------
__global__ __launch_bounds__(256) void scatter_kernel(
    const int* __restrict__ src, const int* __restrict__ dst,
    const float* __restrict__ h, float* __restrict__ agg)
{
    const int wid = (blockIdx.x * 256 + threadIdx.x) >> 6;  // edge id
    const int lane = threadIdx.x & 63;
    if (wid < N_EDGES) {
        const int s = src[wid], d = dst[wid];
        atomicAdd(&agg[(size_t)d * HID + lane], h[(size_t)s * HID + lane]);
    }
}

// ---------------------------------------------------------------------------
// Fused GIN MLP: z = h+agg; t1 = relu(bn1(z@W1+b1)); h = relu(bn2(t1@W2+b2)).
// Two chained register-blocked GEMMs; t1 round-trips through the Z tile.
// ---------------------------------------------------------------------------
__global__ __launch_bounds__(256) void mlp_kernel(
    const float* __restrict__ w1, const float* __restrict__ b1,
    const float* __restrict__ g1, const float* __restrict__ bb1,
    const float* __restrict__ m1, const float* __restrict__ v1,
    const float* __restrict__ w2, const float* __restrict__ b2,
    const float* __restrict__ g2, const float* __restrict__ bb2,
    const float* __restrict__ m2, const float* __restrict__ v2,
    float* __restrict__ h, float* __restrict__ agg, int zero_agg)
{
    __shared__ float Z[TILE_N * ZSTRIDE];   // 33792 B
    __shared__ float Wl[HID * HID];         // 16384 B (W1 then W2)
    const int t = threadIdx.x;
    const int cgrp = t & 15, ngrp = t >> 4;
    const int c0 = cgrp * 4;
    const int base = blockIdx.x * TILE_N;

    // stage z = h + agg (and zero agg); 64 rows x 16 float4
    const float4 zero4 = make_float4(0.f, 0.f, 0.f, 0.f);
    #pragma unroll
    for (int i = 0; i < 4; i++) {
        const int idx = t + i * 256;            // 0..1023
        const int n = idx >> 4, k4 = idx & 15;
        const size_t o = (size_t)(base + n) * HID + k4 * 4;
        const float4 hv = *(const float4*)(h + o);
        const float4 av = *(const float4*)(agg + o);
        float4 zv;
        zv.x = hv.x + av.x; zv.y = hv.y + av.y;
        zv.z = hv.z + av.z; zv.w = hv.w + av.w;
        *(float4*)(&Z[n * ZSTRIDE + k4 * 4]) = zv;
        if (zero_agg) *(float4*)(agg + o) = zero4;
    }
    // stage W1
    #pragma unroll
    for (int i = 0; i < 4; i++) {
        const int idx = t + i * 256;
        const int k = idx >> 4, k4 = idx & 15;
        *(float4*)(&Wl[k * HID + k4 * 4]) = *(const float4*)(w1 + (size_t)k * HID + k4 * 4);
    }
    float s1[4], c1[4], s2[4], c2[4];
    #pragma unroll
    for (int cc = 0; cc < 4; cc++) {
        const int c = c0 + cc;
        const float sa = g1[c] * rsqrtf(v1[c] + BN_EPS);
        s1[cc] = sa; c1[cc] = b1[c] * sa + bb1[c] - m1[c] * sa;
        const float sb = g2[c] * rsqrtf(v2[c] + BN_EPS);
        s2[cc] = sb; c2[cc] = b2[c] * sb + bb2[c] - m2[c] * sb;
    }
    __syncthreads();

    // GEMM1
    float acc[4][4] = {};
    #pragma unroll
    for (int k4 = 0; k4 < 16; k4++) {
        float4 zv[4], wv[4];
        #pragma unroll
        for (int j = 0; j < 4; j++)
            zv[j] = *(const float4*)(&Z[(ngrp + 16 * j) * ZSTRIDE + k4 * 4]);
        #pragma unroll
        for (int i = 0; i < 4; i++)
            wv[i] = *(const float4*)(&Wl[(k4 * 4 + i) * HID + c0]);
        #pragma unroll
        for (int j = 0; j < 4; j++) {
            const float z0 = zv[j].x, z1 = zv[j].y, z2 = zv[j].z, z3 = zv[j].w;
            acc[j][0] += z0 * wv[0].x + z1 * wv[1].x + z2 * wv[2].x + z3 * wv[3].x;
            acc[j][1] += z0 * wv[0].y + z1 * wv[1].y + z2 * wv[2].y + z3 * wv[3].y;
            acc[j][2] += z0 * wv[0].z + z1 * wv[1].z + z2 * wv[2].z + z3 * wv[3].z;
            acc[j][3] += z0 * wv[0].w + z1 * wv[1].w + z2 * wv[2].w + z3 * wv[3].w;
        }
    }
    __syncthreads();   // all GEMM1 reads of Z/Wl done

    // t1 = relu(bn1(acc)) back into Z; stage W2 into Wl
    #pragma unroll
    for (int j = 0; j < 4; j++) {
        const int n = ngrp + 16 * j;
        float4 o;
        o.x = fmaxf(acc[j][0] * s1[0] + c1[0], 0.f);
        o.y = fmaxf(acc[j][1] * s1[1] + c1[1], 0.f);
        o.z = fmaxf(acc[j][2] * s1[2] + c1[2], 0.f);
        o.w = fmaxf(acc[j][3] * s1[3] + c1[3], 0.f);
        *(float4*)(&Z[n * ZSTRIDE + c0]) = o;
    }
    #pragma unroll
    for (int i = 0; i < 4; i++) {
        const int idx = t + i * 256;
        const int k = idx >> 4, k4 = idx & 15;
        *(float4*)(&Wl[k * HID + k4 * 4]) = *(const float4*)(w2 + (size_t)k * HID + k4 * 4);
    }
    __syncthreads();

    // GEMM2
    float acc2[4][4] = {};
    #pragma unroll
    for (int k4 = 0; k4 < 16; k4++) {
        float4 zv[4], wv[4];
        #pragma unroll
        for (int j = 0; j < 4; j++)
            zv[j] = *(const float4*)(&Z[(ngrp + 16 * j) * ZSTRIDE + k4 * 4]);
        #pragma unroll
        for (int i = 0; i < 4; i++)
            wv[i] = *(const float4*)(&Wl[(k4 * 4 + i) * HID + c0]);
        #pragma unroll
        for (int j = 0; j < 4; j++) {
            const float z0 = zv[j].x, z1 = zv[j].y, z2 = zv[j].z, z3 = zv[j].w;
            acc2[j][0] += z0 * wv[0].x + z1 * wv[1].x + z2 * wv[2].x + z3 * wv[3].x;
            acc2[j][1] += z0 * wv[0].y + z1 * wv[1].y + z2 * wv[2].y + z3 * wv[3].y;
            acc2[j][2] += z0 * wv[0].z + z1 * wv[1].z + z2 * wv[2].z + z3 * wv[3].z;
            acc2[j][3] += z0 * wv[0].w + z1 * wv[1].w + z2 * wv[2].w + z3 * wv[3].w;
        }
    }

    #pragma unroll
    for (int j = 0; j < 4; j++) {
        const int n = base + ngrp + 16 * j;
        float4 o;
        o.x = fmaxf(acc2[j][0] * s2[0] + c2[0], 0.f);
        o.y = fmaxf(acc2[j][1] * s2[1] + c2[1], 0.f);
        o.z = fmaxf(acc2[j][2] * s2[2] + c2[2], 0.f);
        o.w = fmaxf(acc2[j][3] * s2[3] + c2[3], 0.f);
        *(float4*)(h + (size_t)n * HID + c0) = o;
    }
}

// ---------------------------------------------------------------------------
// Pool: batch is sorted; accumulate runs in registers, flush one atomic per
// (wave, graph-transition). Lane = channel.
// ---------------------------------------------------------------------------
__global__ __launch_bounds__(256) void pool_kernel(
    const float* __restrict__ h, const int* __restrict__ batch,
    float* __restrict__ pooled /*[G,64]*/, float* __restrict__ cnt /*[G]*/)
{
    const int CHUNK = 256;
    const int wid = (blockIdx.x * 256 + threadIdx.x) >> 6;
    const int lane = threadIdx.x & 63;
    const int start = wid * CHUNK;
    if (start >= N_NODES) return;
    const int end = (start + CHUNK < N_NODES) ? (start + CHUNK) : N_NODES;
    int cur = batch[start];
    float acc = 0.f, c = 0.f;
    for (int n = start; n < end; n++) {
        const int g = batch[n];             // wave-uniform (sorted batch)
        if (g != cur) {
            atomicAdd(&pooled[(size_t)cur * HID + lane], acc);
            if (lane == 0) atomicAdd(&cnt[cur], c);
            cur = g; acc = 0.f; c = 0.f;
        }
        acc += h[(size_t)n * HID + lane];
        c += 1.f;
    }
    atomicAdd(&pooled[(size_t)cur * HID + lane], acc);
    if (lane == 0) atomicAdd(&cnt[cur], c);
}

// ---------------------------------------------------------------------------
// Classifier: per graph, p = pooled/cnt; out = relu(p@W1+b1)@W2+b2.
// ---------------------------------------------------------------------------
__global__ __launch_bounds__(64) void cls_kernel(
    const float* __restrict__ pooled, const float* __restrict__ cnt,
    const float* __restrict__ w1, const float* __restrict__ b1, // [64,32],[32]
    const float* __restrict__ w2, const float* __restrict__ b2, // [32,6],[6]
    float* __restrict__ out)      // [G,6]
{
    const int g = blockIdx.x;
    const int lane = threadIdx.x;
    const float c = cnt[g];
    const float p = pooled[(size_t)g * HID + lane] / fmaxf(c, 1.f);
    float acc = (lane < 32) ? b1[lane] : 0.f;
    #pragma unroll
    for (int k = 0; k < 64; k++) {
        const float pk = __shfl(p, k, 64);
        if (lane < 32) acc += pk * w1[k * 32 + lane];
    }
    const float hmid = fmaxf(acc, 0.f);
    float acc2 = (lane < NCLS) ? b2[lane] : 0.f;
    #pragma unroll
    for (int k = 0; k < 32; k++) {
        const float hk = __shfl(hmid, k, 64);
        if (lane < NCLS) acc2 += hk * w2[k * NCLS + lane];
    }
    if (lane < NCLS) out[(size_t)g * NCLS + lane] = acc2;
}

// ---------------------------------------------------------------------------
extern "C" void kernel_launch(void* const* d_in, const int* in_sizes, int n_in,
                              void* d_out, int out_size, void* d_ws, size_t ws_size,
                              hipStream_t stream) {
    const float* x     = (const float*)d_in[0];
    const int*   ei    = (const int*)d_in[1];            // [2,E]
    const int*   batch = (const int*)d_in[2];
    const float* emb_w = (const float*)d_in[3];
    const float* emb_b = (const float*)d_in[4];
    const float* ibn_g = (const float*)d_in[5];
    const float* ibn_b = (const float*)d_in[6];
    const float* ibn_m = (const float*)d_in[7];
    const float* ibn_v = (const float*)d_in[8];
    const float* fc1_w = (const float*)d_in[9];
    const float* fc1_b = (const float*)d_in[10];
    const float* mbn_g = (const float*)d_in[11];
    const float* mbn_b = (const float*)d_in[12];
    const float* mbn_m = (const float*)d_in[13];
    const float* mbn_v = (const float*)d_in[14];
    const float* fc2_w = (const float*)d_in[15];
    const float* fc2_b = (const float*)d_in[16];
    const float* obn_g = (const float*)d_in[17];
    const float* obn_b = (const float*)d_in[18];
    const float* obn_m = (const float*)d_in[19];
    const float* obn_v = (const float*)d_in[20];
    const float* cls1w = (const float*)d_in[21];
    const float* cls1b = (const float*)d_in[22];
    const float* cls2w = (const float*)d_in[23];
    const float* cls2b = (const float*)d_in[24];

    float* h      = (float*)d_ws;
    float* agg    = h + (size_t)N_NODES * HID;
    float* pooled = agg + (size_t)N_NODES * HID;
    float* cnt    = pooled + (size_t)NGRAPH * HID;

    hipMemsetAsync(pooled, 0, (size_t)(NGRAPH * HID + NGRAPH) * sizeof(float), stream);

    const int gemm_blocks = N_NODES / TILE_N;   // 3125 (200000 % 64 == 0)
    embed_kernel<<<gemm_blocks, 256, 0, stream>>>(x, emb_w, emb_b,
                                                  ibn_g, ibn_b, ibn_m, ibn_v, h, agg);

    for (int i = 0; i < 3; i++) {
        scatter_kernel<<<N_EDGES / 4, 256, 0, stream>>>(ei, ei + N_EDGES, h, agg);
        mlp_kernel<<<gemm_blocks, 256, 0, stream>>>(
            fc1_w + i * HID * HID, fc1_b + i * HID,
            mbn_g + i * HID, mbn_b + i * HID, mbn_m + i * HID, mbn_v + i * HID,
            fc2_w + i * HID * HID, fc2_b + i * HID,
            obn_g + i * HID, obn_b + i * HID, obn_m + i * HID, obn_v + i * HID,
            h, agg, (i < 2) ? 1 : 0);
    }

    const int pool_waves = (N_NODES + 255) / 256;    // 782 waves
    pool_kernel<<<(pool_waves + 3) / 4, 256, 0, stream>>>(h, batch, pooled, cnt);

    cls_kernel<<<NGRAPH, 64, 0, stream>>>(pooled, cnt, cls1w, cls1b, cls2w, cls2b,
                                          (float*)d_out);
}

// Round 4
// 1090.289 us; speedup vs baseline: 2.3368x; 1.2587x over previous
//
#include <hip/hip_runtime.h>
#include <hip/hip_bf16.h>

#define N_NODES 200000
#define N_EDGES 1200000
#define IN_DIM  128
#define HID     64
#define NGRAPH  1024
#define NCLS    6
#define BN_EPS  1e-5f

#define TILE_N   64          // nodes per GEMM block
#define XSTRIDE  132         // embed x-tile row stride (floats), bank-safe
#define ZS       68          // mlp z-tile row stride (floats), bank-safe

#define SCAN_CHUNK 1024
#define NBLK_SCAN ((N_NODES + SCAN_CHUNK - 1) / SCAN_CHUNK)   // 196

// ===========================================================================
// CSR build: deg histogram -> 3-step scan -> bucket scatter of src ids.
// ===========================================================================
__global__ __launch_bounds__(256) void hist_kernel(
    const int* __restrict__ dst, int* __restrict__ deg)
{
    const int e = blockIdx.x * 256 + threadIdx.x;
    if (e < N_EDGES) atomicAdd(&deg[dst[e]], 1);
}

__global__ __launch_bounds__(256) void scan_sum_kernel(
    const int* __restrict__ deg, int* __restrict__ bsum)
{
    __shared__ int sd[256];
    const int b = blockIdx.x, t = threadIdx.x;
    const int base = b * SCAN_CHUNK;
    int s = 0;
    #pragma unroll
    for (int i = 0; i < SCAN_CHUNK / 256; i++) {
        const int idx = base + t + i * 256;
        s += (idx < N_NODES) ? deg[idx] : 0;
    }
    sd[t] = s; __syncthreads();
    for (int off = 128; off > 0; off >>= 1) {
        if (t < off) sd[t] += sd[t + off];
        __syncthreads();
    }
    if (t == 0) bsum[b] = sd[0];
}

__global__ __launch_bounds__(256) void scan_block_kernel(
    const int* __restrict__ bsum, int* __restrict__ boff, int* __restrict__ offs)
{
    __shared__ int sd[256];
    const int t = threadIdx.x;
    const int v = (t < NBLK_SCAN) ? bsum[t] : 0;
    sd[t] = v; __syncthreads();
    for (int off = 1; off < 256; off <<= 1) {
        const int u = (t >= off) ? sd[t - off] : 0;
        __syncthreads();
        sd[t] += u;
        __syncthreads();
    }
    if (t < NBLK_SCAN) boff[t] = sd[t] - v;   // exclusive
    if (t == 0) offs[N_NODES] = N_EDGES;
}

__global__ __launch_bounds__(256) void scan_scatter_kernel(
    const int* __restrict__ deg, const int* __restrict__ boff, int* __restrict__ offs)
{
    __shared__ int sd[256];
    const int b = blockIdx.x, t = threadIdx.x;
    const int base = b * SCAN_CHUNK + t * 4;
    int d0 = 0, d1 = 0, d2 = 0, d3 = 0;
    if (base + 0 < N_NODES) d0 = deg[base + 0];
    if (base + 1 < N_NODES) d1 = deg[base + 1];
    if (base + 2 < N_NODES) d2 = deg[base + 2];
    if (base + 3 < N_NODES) d3 = deg[base + 3];
    const int ts = d0 + d1 + d2 + d3;
    sd[t] = ts; __syncthreads();
    for (int off = 1; off < 256; off <<= 1) {
        const int u = (t >= off) ? sd[t - off] : 0;
        __syncthreads();
        sd[t] += u;
        __syncthreads();
    }
    const int excl = sd[t] - ts + boff[b];
    if (base + 0 < N_NODES) offs[base + 0] = excl;
    if (base + 1 < N_NODES) offs[base + 1] = excl + d0;
    if (base + 2 < N_NODES) offs[base + 2] = excl + d0 + d1;
    if (base + 3 < N_NODES) offs[base + 3] = excl + d0 + d1 + d2;
}

__global__ __launch_bounds__(256) void bucket_kernel(
    const int* __restrict__ src, const int* __restrict__ dst,
    int* __restrict__ cursor, int* __restrict__ csr_src)
{
    const int e = blockIdx.x * 256 + threadIdx.x;
    if (e < N_EDGES) {
        const int pos = atomicAdd(&cursor[dst[e]], 1);
        csr_src[pos] = src[e];
    }
}

// ===========================================================================
// Embed: h0 = relu(bn(x @ W + b)). Register-blocked LDS GEMM, K=128 in halves.
// ===========================================================================
__global__ __launch_bounds__(256) void embed_kernel(
    const float* __restrict__ x,      // [N,128]
    const float* __restrict__ w,      // [128,64]
    const float* __restrict__ bias,
    const float* __restrict__ bn_g, const float* __restrict__ bn_b,
    const float* __restrict__ bn_m, const float* __restrict__ bn_v,
    float* __restrict__ h)            // [N,64]
{
    __shared__ float Z[TILE_N * XSTRIDE];   // 33792 B
    __shared__ float Wl[64 * HID];          // 16384 B
    const int t = threadIdx.x;
    const int cgrp = t & 15, ngrp = t >> 4;
    const int c0 = cgrp * 4;
    const int base = blockIdx.x * TILE_N;

    #pragma unroll
    for (int i = 0; i < 8; i++) {
        const int idx = t + i * 256;            // 0..2047
        const int n = idx >> 5, k4 = idx & 31;
        *(float4*)(&Z[n * XSTRIDE + k4 * 4]) =
            *(const float4*)(x + (size_t)(base + n) * IN_DIM + k4 * 4);
    }

    float scale[4], shift[4];
    #pragma unroll
    for (int cc = 0; cc < 4; cc++) {
        const int c = c0 + cc;
        const float s = bn_g[c] * rsqrtf(bn_v[c] + BN_EPS);
        scale[cc] = s;
        shift[cc] = bias[c] * s + bn_b[c] - bn_m[c] * s;
    }

    float acc[4][4] = {};
    for (int kh = 0; kh < 2; kh++) {
        __syncthreads();
        #pragma unroll
        for (int i = 0; i < 4; i++) {
            const int idx = t + i * 256;
            const int k = idx >> 4, k4 = idx & 15;
            *(float4*)(&Wl[k * HID + k4 * 4]) =
                *(const float4*)(w + (size_t)(kh * 64 + k) * HID + k4 * 4);
        }
        __syncthreads();

        #pragma unroll
        for (int k4 = 0; k4 < 16; k4++) {
            float4 zv[4], wv[4];
            #pragma unroll
            for (int j = 0; j < 4; j++)
                zv[j] = *(const float4*)(&Z[(ngrp + 16 * j) * XSTRIDE + (kh * 16 + k4) * 4]);
            #pragma unroll
            for (int i = 0; i < 4; i++)
                wv[i] = *(const float4*)(&Wl[(k4 * 4 + i) * HID + c0]);
            #pragma unroll
            for (int j = 0; j < 4; j++) {
                const float z0 = zv[j].x, z1 = zv[j].y, z2 = zv[j].z, z3 = zv[j].w;
                acc[j][0] += z0 * wv[0].x + z1 * wv[1].x + z2 * wv[2].x + z3 * wv[3].x;
                acc[j][1] += z0 * wv[0].y + z1 * wv[1].y + z2 * wv[2].y + z3 * wv[3].y;
                acc[j][2] += z0 * wv[0].z + z1 * wv[1].z + z2 * wv[2].z + z3 * wv[3].z;
                acc[j][3] += z0 * wv[0].w + z1 * wv[1].w + z2 * wv[2].w + z3 * wv[3].w;
            }
        }
    }

    #pragma unroll
    for (int j = 0; j < 4; j++) {
        const int n = base + ngrp + 16 * j;
        float4 o;
        o.x = fmaxf(acc[j][0] * scale[0] + shift[0], 0.f);
        o.y = fmaxf(acc[j][1] * scale[1] + shift[1], 0.f);
        o.z = fmaxf(acc[j][2] * scale[2] + shift[2], 0.f);
        o.w = fmaxf(acc[j][3] * scale[3] + shift[3], 0.f);
        *(float4*)(h + (size_t)n * HID + c0) = o;
    }
}

// ===========================================================================
// Fused GIN layer: z = h_in + CSR-gather-sum(h_in); two GEMMs; h_out.
// Ping-pong buffers make remote reads race-free.
// ===========================================================================
__global__ __launch_bounds__(256) void agg_mlp_kernel(
    const float* __restrict__ hin, float* __restrict__ hout,
    const int* __restrict__ offs, const int* __restrict__ csr,
    const float* __restrict__ w1, const float* __restrict__ b1,
    const float* __restrict__ g1, const float* __restrict__ bb1,
    const float* __restrict__ m1, const float* __restrict__ v1,
    const float* __restrict__ w2, const float* __restrict__ b2,
    const float* __restrict__ g2, const float* __restrict__ bb2,
    const float* __restrict__ m2, const float* __restrict__ v2)
{
    __shared__ float Z[TILE_N * ZS];        // 17408 B
    __shared__ float Wl[HID * HID];         // 16384 B
    const int t = threadIdx.x;
    const int lane = t & 63, w = t >> 6;
    const int cgrp = t & 15, ngrp = t >> 4;
    const int c0 = cgrp * 4;
    const int base = blockIdx.x * TILE_N;

    // stage W1 (independent loads issued before the latency-heavy gather)
    #pragma unroll
    for (int i = 0; i < 4; i++) {
        const int idx = t + i * 256;
        const int k = idx >> 4, k4 = idx & 15;
        *(float4*)(&Wl[k * HID + k4 * 4]) = *(const float4*)(w1 + (size_t)k * HID + k4 * 4);
    }

    // aggregation: wave w handles nodes [w*16, w*16+16); lane = channel
    for (int nn = w * 16; nn < w * 16 + 16; nn++) {
        const int row = base + nn;
        const int e0 = offs[row], e1 = offs[row + 1];
        float acc = hin[(size_t)row * HID + lane];
        int e = e0;
        for (; e + 1 < e1; e += 2) {          // 2-deep pipeline: 2 loads in flight
            const int s0 = csr[e], s1 = csr[e + 1];
            const float v0 = hin[(size_t)s0 * HID + lane];
            const float v1 = hin[(size_t)s1 * HID + lane];
            acc += v0 + v1;
        }
        if (e < e1) acc += hin[(size_t)csr[e] * HID + lane];
        Z[nn * ZS + lane] = acc;
    }

    float s1c[4], c1c[4], s2c[4], c2c[4];
    #pragma unroll
    for (int cc = 0; cc < 4; cc++) {
        const int c = c0 + cc;
        const float sa = g1[c] * rsqrtf(v1[c] + BN_EPS);
        s1c[cc] = sa; c1c[cc] = b1[c] * sa + bb1[c] - m1[c] * sa;
        const float sb = g2[c] * rsqrtf(v2[c] + BN_EPS);
        s2c[cc] = sb; c2c[cc] = b2[c] * sb + bb2[c] - m2[c] * sb;
    }
    __syncthreads();

    // GEMM1
    float acc1[4][4] = {};
    #pragma unroll
    for (int k4 = 0; k4 < 16; k4++) {
        float4 zv[4], wv[4];
        #pragma unroll
        for (int j = 0; j < 4; j++)
            zv[j] = *(const float4*)(&Z[(ngrp + 16 * j) * ZS + k4 * 4]);
        #pragma unroll
        for (int i = 0; i < 4; i++)
            wv[i] = *(const float4*)(&Wl[(k4 * 4 + i) * HID + c0]);
        #pragma unroll
        for (int j = 0; j < 4; j++) {
            const float z0 = zv[j].x, z1 = zv[j].y, z2 = zv[j].z, z3 = zv[j].w;
            acc1[j][0] += z0 * wv[0].x + z1 * wv[1].x + z2 * wv[2].x + z3 * wv[3].x;
            acc1[j][1] += z0 * wv[0].y + z1 * wv[1].y + z2 * wv[2].y + z3 * wv[3].y;
            acc1[j][2] += z0 * wv[0].z + z1 * wv[1].z + z2 * wv[2].z + z3 * wv[3].z;
            acc1[j][3] += z0 * wv[0].w + z1 * wv[1].w + z2 * wv[2].w + z3 * wv[3].w;
        }
    }
    __syncthreads();   // GEMM1 reads of Z/Wl done

    // t1 = relu(bn1(.)) back into Z; stage W2
    #pragma unroll
    for (int j = 0; j < 4; j++) {
        const int n = ngrp + 16 * j;
        float4 o;
        o.x = fmaxf(acc1[j][0] * s1c[0] + c1c[0], 0.f);
        o.y = fmaxf(acc1[j][1] * s1c[1] + c1c[1], 0.f);
        o.z = fmaxf(acc1[j][2] * s1c[2] + c1c[2], 0.f);
        o.w = fmaxf(acc1[j][3] * s1c[3] + c1c[3], 0.f);
        *(float4*)(&Z[n * ZS + c0]) = o;
    }
    #pragma unroll
    for (int i = 0; i < 4; i++) {
        const int idx = t + i * 256;
        const int k = idx >> 4, k4 = idx & 15;
        *(float4*)(&Wl[k * HID + k4 * 4]) = *(const float4*)(w2 + (size_t)k * HID + k4 * 4);
    }
    __syncthreads();

    // GEMM2
    float acc2[4][4] = {};
    #pragma unroll
    for (int k4 = 0; k4 < 16; k4++) {
        float4 zv[4], wv[4];
        #pragma unroll
        for (int j = 0; j < 4; j++)
            zv[j] = *(const float4*)(&Z[(ngrp + 16 * j) * ZS + k4 * 4]);
        #pragma unroll
        for (int i = 0; i < 4; i++)
            wv[i] = *(const float4*)(&Wl[(k4 * 4 + i) * HID + c0]);
        #pragma unroll
        for (int j = 0; j < 4; j++) {
            const float z0 = zv[j].x, z1 = zv[j].y, z2 = zv[j].z, z3 = zv[j].w;
            acc2[j][0] += z0 * wv[0].x + z1 * wv[1].x + z2 * wv[2].x + z3 * wv[3].x;
            acc2[j][1] += z0 * wv[0].y + z1 * wv[1].y + z2 * wv[2].y + z3 * wv[3].y;
            acc2[j][2] += z0 * wv[0].z + z1 * wv[1].z + z2 * wv[2].z + z3 * wv[3].z;
            acc2[j][3] += z0 * wv[0].w + z1 * wv[1].w + z2 * wv[2].w + z3 * wv[3].w;
        }
    }

    #pragma unroll
    for (int j = 0; j < 4; j++) {
        const int n = base + ngrp + 16 * j;
        float4 o;
        o.x = fmaxf(acc2[j][0] * s2c[0] + c2c[0], 0.f);
        o.y = fmaxf(acc2[j][1] * s2c[1] + c2c[1], 0.f);
        o.z = fmaxf(acc2[j][2] * s2c[2] + c2c[2], 0.f);
        o.w = fmaxf(acc2[j][3] * s2c[3] + c2c[3], 0.f);
        *(float4*)(hout + (size_t)n * HID + c0) = o;
    }
}

// ===========================================================================
// Pool: batch sorted; register run-accumulation, one atomic per transition.
// ===========================================================================
__global__ __launch_bounds__(256) void pool_kernel(
    const float* __restrict__ h, const int* __restrict__ batch,
    float* __restrict__ pooled, float* __restrict__ cnt)
{
    const int CHUNK = 256;
    const int wid = (blockIdx.x * 256 + threadIdx.x) >> 6;
    const int lane = threadIdx.x & 63;
    const int start = wid * CHUNK;
    if (start >= N_NODES) return;
    const int end = (start + CHUNK < N_NODES) ? (start + CHUNK) : N_NODES;
    int cur = batch[start];
    float acc = 0.f, c = 0.f;
    for (int n = start; n < end; n++) {
        const int g = batch[n];
        if (g != cur) {
            atomicAdd(&pooled[(size_t)cur * HID + lane], acc);
            if (lane == 0) atomicAdd(&cnt[cur], c);
            cur = g; acc = 0.f; c = 0.f;
        }
        acc += h[(size_t)n * HID + lane];
        c += 1.f;
    }
    atomicAdd(&pooled[(size_t)cur * HID + lane], acc);
    if (lane == 0) atomicAdd(&cnt[cur], c);
}

// ===========================================================================
// Classifier
// ===========================================================================
__global__ __launch_bounds__(64) void cls_kernel(
    const float* __restrict__ pooled, const float* __restrict__ cnt,
    const float* __restrict__ w1, const float* __restrict__ b1,
    const float* __restrict__ w2, const float* __restrict__ b2,
    float* __restrict__ out)
{
    const int g = blockIdx.x;
    const int lane = threadIdx.x;
    const float c = cnt[g];
    const float p = pooled[(size_t)g * HID + lane] / fmaxf(c, 1.f);
    float acc = (lane < 32) ? b1[lane] : 0.f;
    #pragma unroll
    for (int k = 0; k < 64; k++) {
        const float pk = __shfl(p, k, 64);
        if (lane < 32) acc += pk * w1[k * 32 + lane];
    }
    const float hmid = fmaxf(acc, 0.f);
    float acc2 = (lane < NCLS) ? b2[lane] : 0.f;
    #pragma unroll
    for (int k = 0; k < 32; k++) {
        const float hk = __shfl(hmid, k, 64);
        if (lane < NCLS) acc2 += hk * w2[k * NCLS + lane];
    }
    if (lane < NCLS) out[(size_t)g * NCLS + lane] = acc2;
}

// ===========================================================================
extern "C" void kernel_launch(void* const* d_in, const int* in_sizes, int n_in,
                              void* d_out, int out_size, void* d_ws, size_t ws_size,
                              hipStream_t stream) {
    const float* x     = (const float*)d_in[0];
    const int*   ei    = (const int*)d_in[1];            // [2,E]
    const int*   batch = (const int*)d_in[2];
    const float* emb_w = (const float*)d_in[3];
    const float* emb_b = (const float*)d_in[4];
    const float* ibn_g = (const float*)d_in[5];
    const float* ibn_b = (const float*)d_in[6];
    const float* ibn_m = (const float*)d_in[7];
    const float* ibn_v = (const float*)d_in[8];
    const float* fc1_w = (const float*)d_in[9];
    const float* fc1_b = (const float*)d_in[10];
    const float* mbn_g = (const float*)d_in[11];
    const float* mbn_b = (const float*)d_in[12];
    const float* mbn_m = (const float*)d_in[13];
    const float* mbn_v = (const float*)d_in[14];
    const float* fc2_w = (const float*)d_in[15];
    const float* fc2_b = (const float*)d_in[16];
    const float* obn_g = (const float*)d_in[17];
    const float* obn_b = (const float*)d_in[18];
    const float* obn_m = (const float*)d_in[19];
    const float* obn_v = (const float*)d_in[20];
    const float* cls1w = (const float*)d_in[21];
    const float* cls1b = (const float*)d_in[22];
    const float* cls2w = (const float*)d_in[23];
    const float* cls2b = (const float*)d_in[24];

    float* h0     = (float*)d_ws;                        // 12.8M floats
    float* h1     = h0 + (size_t)N_NODES * HID;          // 12.8M floats
    float* pooled = h1 + (size_t)N_NODES * HID;          // 65536
    float* cnt    = pooled + NGRAPH * HID;               // 1024
    int*   deg    = (int*)(cnt + NGRAPH);                // 200000 (reused as cursor)
    int*   offs   = deg + N_NODES;                       // 200001
    int*   bsum   = offs + (N_NODES + 1);                // 196
    int*   boff   = bsum + NBLK_SCAN;                    // 196
    int*   csr    = boff + NBLK_SCAN;                    // 1.2M

    const int* src = ei;
    const int* dst = ei + N_EDGES;

    // ---- CSR build (once, reused by all 3 layers) ----
    hipMemsetAsync(deg, 0, N_NODES * sizeof(int), stream);
    hipMemsetAsync(pooled, 0, (size_t)(NGRAPH * HID + NGRAPH) * sizeof(float), stream);
    hist_kernel<<<(N_EDGES + 255) / 256, 256, 0, stream>>>(dst, deg);
    scan_sum_kernel<<<NBLK_SCAN, 256, 0, stream>>>(deg, bsum);
    scan_block_kernel<<<1, 256, 0, stream>>>(bsum, boff, offs);
    scan_scatter_kernel<<<NBLK_SCAN, 256, 0, stream>>>(deg, boff, offs);
    hipMemcpyAsync(deg, offs, N_NODES * sizeof(int), hipMemcpyDeviceToDevice, stream);
    bucket_kernel<<<(N_EDGES + 255) / 256, 256, 0, stream>>>(src, dst, deg, csr);

    // ---- network ----
    const int gemm_blocks = N_NODES / TILE_N;   // 3125
    embed_kernel<<<gemm_blocks, 256, 0, stream>>>(x, emb_w, emb_b,
                                                  ibn_g, ibn_b, ibn_m, ibn_v, h0);

    const float* hin = h0;
    float* hout = h1;
    for (int i = 0; i < 3; i++) {
        agg_mlp_kernel<<<gemm_blocks, 256, 0, stream>>>(
            hin, hout, offs, csr,
            fc1_w + i * HID * HID, fc1_b + i * HID,
            mbn_g + i * HID, mbn_b + i * HID, mbn_m + i * HID, mbn_v + i * HID,
            fc2_w + i * HID * HID, fc2_b + i * HID,
            obn_g + i * HID, obn_b + i * HID, obn_m + i * HID, obn_v + i * HID);
        const float* tmp = hin; hin = hout; hout = (float*)tmp;
    }
    // after 3 layers: result in h1 (h0->h1->h0->h1)

    const int pool_waves = (N_NODES + 255) / 256;
    pool_kernel<<<(pool_waves + 3) / 4, 256, 0, stream>>>(h1, batch, pooled, cnt);

    cls_kernel<<<NGRAPH, 64, 0, stream>>>(pooled, cnt, cls1w, cls1b, cls2w, cls2b,
                                          (float*)d_out);
}